// Round 13
// baseline (74.671 us; speedup 1.0000x reference)
//
#include <hip/hip_runtime.h>

typedef float f32x2 __attribute__((ext_vector_type(2)));
typedef float f32x4 __attribute__((ext_vector_type(4)));

__device__ __forceinline__ float relu_(float v) { return fmaxf(v, 0.f); }
// Intra-wave LDS fence: wave is lockstep; drain our own LDS ops + stop compiler
// reordering across the fence.
__device__ __forceinline__ void wave_sync() {
    asm volatile("s_waitcnt lgkmcnt(0)" ::: "memory");
}
// acc += hv * w   (w folded from SGPR pair; REQUIRES wave-uniform w index)
__device__ __forceinline__ void pk_fma_sw(f32x2& acc, f32x2 hv, f32x2 w) {
    asm("v_pk_fma_f32 %0, %1, %2, %0" : "+v"(acc) : "v"(hv), "s"(w));
}

// PAIRS_A = {0,0,4,1,2,2,6,3} ; PAIRS_B = {4,1,5,5,6,3,7,7} packed as nibbles
#define PA_PACK 0x36221400u
#define PB_PACK 0x77365514u

// ---------------- pre-kernel: yk stored as [ij][half][12] (12-padded halves
// so each half is 16B-aligned: 2 b128 + 1 b64 loads). ws[1536] = c0.
__global__ void yk_kernel(
    const float* __restrict__ mask,
    const float* __restrict__ wm1, const float* __restrict__ bm1,
    const float* __restrict__ wm2, const float* __restrict__ bm2,
    const float* __restrict__ wm3, const float* __restrict__ bm3,
    const float* __restrict__ wk1, const float* __restrict__ bk1,
    const float* __restrict__ wk2, const float* __restrict__ bk2,
    float* __restrict__ ws)
{
    int tid = threadIdx.x;
    int ij = tid >> 2, coff = (tid & 3) * 5;
    int i = ij >> 3, j = ij & 7;
    float m = mask[i * 8 + j];
    float a[4];
#pragma unroll
    for (int q = 0; q < 4; q++) a[q] = relu_(fmaf(m, wm1[q], bm1[q]));
    float b2[20];
#pragma unroll
    for (int c = 0; c < 20; c++) {
        float acc = bm2[c];
#pragma unroll
        for (int q = 0; q < 4; q++) acc = fmaf(a[q], wm2[q * 20 + c], acc);
        b2[c] = relu_(acc);
    }
#pragma unroll
    for (int cc = 0; cc < 5; cc++) {
        int c = coff + cc;
        float acc = bm3[c];
#pragma unroll
        for (int k = 0; k < 20; k++) acc = fmaf(b2[k], wm3[k * 20 + c], acc);
        float y = relu_(acc);
        float wkk = 0.f;
#pragma unroll
        for (int q = 0; q < 8; q++) wkk = fmaf(wk1[c * 8 + q], wk2[q], wkk);
        int half = (c >= 10), cc12 = c - 10 * half;
        ws[ij * 24 + half * 12 + cc12] = y * wkk;
    }
    if (tid == 0) {
        float c0 = bk2[0];
#pragma unroll
        for (int q = 0; q < 8; q++) c0 = fmaf(bk1[q], wk2[q], c0);
        ws[1536] = c0;
    }
}

// ---------------- main kernel: 4 batches/wave, lane=(g,jh,i).
// Every lane computes u[i] AND v[i] with WAVE-UNIFORM weight indices (the jh
// split of weight rows in R12 made the "s"-operand index divergent — never
// again). jh=0 lane writes u row, jh=1 writes v row -> LDS. Stage 4: lane owns
// (i,jh), 4 j's; per j: h as 10 f32x2 from LDS, s2 in two 5-pair half-passes.
// Peak live ~42 floats at every point; NO launch_bounds, NO unions.
// Grid 1024 x 2 grid-stride iterations: balanced persistent occupancy.
__global__ void frap_kernel(
    const float* __restrict__ x,
    const float* __restrict__ wv1, const float* __restrict__ bv1,
    const float* __restrict__ wv2, const float* __restrict__ bv2,
    const float* __restrict__ wp1, const float* __restrict__ bp1,
    const float* __restrict__ wp2, const float* __restrict__ bp2,
    const float* __restrict__ we,  const float* __restrict__ be,
    const float* __restrict__ wc1, const float* __restrict__ bc1,
    const float* __restrict__ wc2, const float* __restrict__ bc2,
    const float* __restrict__ ykg,
    float* __restrict__ out, int Btot)
{
    // Per-(w,g) block stride 322 dwords (322 mod 32 = 2): the 4 g's of a wave
    // land at bank offsets {0,2,4,6} -> worst aliasing on u-reads is 2-way
    // (free, m136); v-reads conflict-free. Rows r*20 within a block.
    __shared__ float s_uv[16 * 322];

    const int tid  = threadIdx.x;
    const int w    = tid >> 6;
    const int lane = tid & 63;
    const int g    = lane >> 4;
    const int jh   = (lane >> 3) & 1;
    const int i    = lane & 7;
    const int grp  = w * 4 + g;
    const int gb   = grp * 322;

    const int pa = (PA_PACK >> (4 * i)) & 15;
    const int pb = (PB_PACK >> (4 * i)) & 15;

    const float c0 = ykg[1536];                       // uniform -> s_load

#pragma unroll 1
    for (int it = 0; it < 2; ++it) {
        const int b  = (it * (int)gridDim.x + (int)blockIdx.x) * 16 + grp;
        const int bb = (b < Btot) ? b : (Btot - 1);   // clamp loads; guard stores

        // ---- stage 1: cat rows pa and pb (weights uniform -> s_load) ----
        float ca[8], cb[8];
        {
            const float xva = x[bb * 16 + pa];
            const float xpa = x[bb * 16 + 8 + pa];
            const float xvb = x[bb * 16 + pb];
            const float xpb = x[bb * 16 + 8 + pb];

            float t0 = relu_(fmaf(xva, wv1[0], bv1[0]));
            float t1 = relu_(fmaf(xva, wv1[1], bv1[1]));
#pragma unroll
            for (int q = 0; q < 4; q++)
                ca[q] = relu_(fmaf(t0, wv2[q], fmaf(t1, wv2[4 + q], bv2[q])));
            float p0 = relu_(fmaf(xpa, wp1[0], bp1[0]));
            float p1 = relu_(fmaf(xpa, wp1[1], bp1[1]));
#pragma unroll
            for (int q = 0; q < 4; q++)
                ca[4 + q] = relu_(fmaf(p0, wp2[q], fmaf(p1, wp2[4 + q], bp2[q])));

            float s0 = relu_(fmaf(xvb, wv1[0], bv1[0]));
            float s1 = relu_(fmaf(xvb, wv1[1], bv1[1]));
#pragma unroll
            for (int q = 0; q < 4; q++)
                cb[q] = relu_(fmaf(s0, wv2[q], fmaf(s1, wv2[4 + q], bv2[q])));
            float r0 = relu_(fmaf(xpb, wp1[0], bp1[0]));
            float r1 = relu_(fmaf(xpb, wp1[1], bp1[1]));
#pragma unroll
            for (int q = 0; q < 4; q++)
                cb[4 + q] = relu_(fmaf(r0, wp2[q], fmaf(r1, wp2[4 + q], bp2[q])));
        }

        // ---- stage 2: pd row i (scalar v_fmac, SGPR weights, uniform) ----
        float pd[16];
#pragma unroll
        for (int k = 0; k < 16; k++) {
            float da = be[k], db = be[k];
#pragma unroll
            for (int f = 0; f < 8; f++) {
                const float wf = we[f * 16 + k];      // uniform -> s_load
                da = fmaf(ca[f], wf, da);
                db = fmaf(cb[f], wf, db);
            }
            pd[k] = relu_(da) + relu_(db);
        }

        // ---- stage 3: every lane computes u[i] AND v[i] (uniform weights);
        //      jh=0 writes u row i, jh=1 writes v row i. Two c-half-passes.
#pragma unroll
        for (int half = 0; half < 2; ++half) {
            f32x2 aU[5], aV[5];
#pragma unroll
            for (int c = 0; c < 5; c++) {
                aU[c] = *(const f32x2*)&bc1[half * 10 + 2 * c];
                aV[c].x = 0.f; aV[c].y = 0.f;
            }
#pragma unroll
            for (int k = 0; k < 16; k++) {
                f32x2 pv; pv.x = pd[k]; pv.y = pd[k];
#pragma unroll
                for (int c = 0; c < 5; c++) {
                    pk_fma_sw(aU[c], pv,
                              *(const f32x2*)&wc1[k * 20 + half * 10 + 2 * c]);
                    pk_fma_sw(aV[c], pv,
                              *(const f32x2*)&wc1[(16 + k) * 20 + half * 10 + 2 * c]);
                }
            }
            if (jh == 0) {
                float* du = &s_uv[gb + i * 20 + half * 10];
#pragma unroll
                for (int c = 0; c < 5; c++) *(f32x2*)&du[2 * c] = aU[c];
            } else {
                float* dv = &s_uv[gb + (8 + i) * 20 + half * 10];
#pragma unroll
                for (int c = 0; c < 5; c++) *(f32x2*)&dv[2 * c] = aV[c];
            }
        }
        wave_sync();   // per-wave LDS region; lockstep => visible wave-wide

        // ---- stage 4: lane owns (i, jh); four iterations, one j each ----
#pragma unroll 1
        for (int t = 0; t < 4; ++t) {
            const int j = jh * 4 + t;
            const float* ur = &s_uv[gb + i * 20];
            const float* vr = &s_uv[gb + (8 + j) * 20];

            f32x2 h[10];
#pragma unroll
            for (int kk = 0; kk < 10; ++kk) {
                f32x2 uu = *(const f32x2*)&ur[2 * kk];   // ds_read_b64 (2-way=free)
                f32x2 vv = *(const f32x2*)&vr[2 * kk];   // ds_read_b64 (bcast)
                uu += vv;                                 // v_pk_add_f32
                h[kk].x = relu_(uu.x);
                h[kk].y = relu_(uu.y);
            }

            float z = c0;
#pragma unroll
            for (int half = 0; half < 2; ++half) {
                f32x2 s[5];
#pragma unroll
                for (int c = 0; c < 5; c++)
                    s[c] = *(const f32x2*)&bc2[half * 10 + 2 * c];
#pragma unroll
                for (int k = 0; k < 20; k++) {
                    const float hk = (k & 1) ? h[k >> 1].y : h[k >> 1].x;
                    f32x2 hv; hv.x = hk; hv.y = hk;
#pragma unroll
                    for (int c = 0; c < 5; c++)
                        pk_fma_sw(s[c], hv,
                                  *(const f32x2*)&wc2[k * 20 + half * 10 + 2 * c]);
                }
                // yk half: 2x b128 + 1x b64 (12-padded, aligned, L1-hot)
                const float* yh = ykg + (i * 8 + j) * 24 + half * 12;
                f32x4 y0 = *(const f32x4*)&yh[0];
                f32x4 y1 = *(const f32x4*)&yh[4];
                f32x2 y2 = *(const f32x2*)&yh[8];
                z = fmaf(relu_(s[0].x), y0.x, z);
                z = fmaf(relu_(s[0].y), y0.y, z);
                z = fmaf(relu_(s[1].x), y0.z, z);
                z = fmaf(relu_(s[1].y), y0.w, z);
                z = fmaf(relu_(s[2].x), y1.x, z);
                z = fmaf(relu_(s[2].y), y1.y, z);
                z = fmaf(relu_(s[3].x), y1.z, z);
                z = fmaf(relu_(s[3].y), y1.w, z);
                z = fmaf(relu_(s[4].x), y2.x, z);
                z = fmaf(relu_(s[4].y), y2.y, z);
            }
            if (b < Btot)
                out[b * 64 + i * 8 + j] = z;
        }
        // next iteration's stage-3 writes are same-wave in-order LDS ops:
        // they cannot pass this iteration's stage-4 reads.
    }
}

extern "C" void kernel_launch(void* const* d_in, const int* in_sizes, int n_in,
                              void* d_out, int out_size, void* d_ws, size_t ws_size,
                              hipStream_t stream) {
    const float* x    = (const float*)d_in[0];
    const float* mask = (const float*)d_in[1];
    const float* wv1  = (const float*)d_in[2];
    const float* bv1  = (const float*)d_in[3];
    const float* wv2  = (const float*)d_in[4];
    const float* bv2  = (const float*)d_in[5];
    const float* wp1  = (const float*)d_in[6];
    const float* bp1  = (const float*)d_in[7];
    const float* wp2  = (const float*)d_in[8];
    const float* bp2  = (const float*)d_in[9];
    const float* we   = (const float*)d_in[10];
    const float* be   = (const float*)d_in[11];
    const float* wc1  = (const float*)d_in[12];
    const float* bc1  = (const float*)d_in[13];
    const float* wc2  = (const float*)d_in[14];
    const float* bc2  = (const float*)d_in[15];
    const float* wm1  = (const float*)d_in[16];
    const float* bm1  = (const float*)d_in[17];
    const float* wm2  = (const float*)d_in[18];
    const float* bm2  = (const float*)d_in[19];
    const float* wm3  = (const float*)d_in[20];
    const float* bm3  = (const float*)d_in[21];
    const float* wk1  = (const float*)d_in[22];
    const float* bk1  = (const float*)d_in[23];
    const float* wk2  = (const float*)d_in[24];
    const float* bk2  = (const float*)d_in[25];
    float* out = (float*)d_out;
    float* ws  = (float*)d_ws;

    int Btot = in_sizes[0] / 16;                 // 32768

    yk_kernel<<<1, 256, 0, stream>>>(mask, wm1, bm1, wm2, bm2, wm3, bm3,
                                     wk1, bk1, wk2, bk2, ws);

    // 1024 blocks x 2 grid-stride iterations x 16 batches = 32768 (balanced)
    frap_kernel<<<1024, 256, 0, stream>>>(
        x, wv1, bv1, wv2, bv2, wp1, bp1, wp2, bp2, we, be,
        wc1, bc1, wc2, bc2, ws, out, Btot);
}

// Round 14
// 42.726 us; speedup vs baseline: 1.7477x; 1.7477x over previous
//
#include <hip/hip_runtime.h>

typedef float f32x2 __attribute__((ext_vector_type(2)));
typedef float f32x4 __attribute__((ext_vector_type(4)));

__device__ __forceinline__ float relu_(float v) { return fmaxf(v, 0.f); }
// Intra-wave LDS fence: wave is lockstep; drain our own LDS ops + stop compiler
// reordering across the fence.
__device__ __forceinline__ void wave_sync() {
    asm volatile("s_waitcnt lgkmcnt(0)" ::: "memory");
}
// VOP3P half-broadcast FMAs (op_sel): kills all splat/extraction movs.
// acc.lo += a.LO*w.lo ; acc.hi += a.LO*w.hi
__device__ __forceinline__ void pk_fma_blo(f32x2& acc, f32x2 a, f32x2 w) {
    asm("v_pk_fma_f32 %0, %1, %2, %0 op_sel:[0,0,0] op_sel_hi:[0,1,1]"
        : "+v"(acc) : "v"(a), "s"(w));
}
// acc.lo += a.HI*w.lo ; acc.hi += a.HI*w.hi
__device__ __forceinline__ void pk_fma_bhi(f32x2& acc, f32x2 a, f32x2 w) {
    asm("v_pk_fma_f32 %0, %1, %2, %0 op_sel:[1,0,0] op_sel_hi:[1,1,1]"
        : "+v"(acc) : "v"(a), "s"(w));
}
// acc += a * b (both VGPR pairs)
__device__ __forceinline__ void pk_fma_vv(f32x2& acc, f32x2 a, f32x2 b) {
    asm("v_pk_fma_f32 %0, %1, %2, %0" : "+v"(acc) : "v"(a), "v"(b));
}

// PAIRS_A = {0,0,4,1,2,2,6,3} ; PAIRS_B = {4,1,5,5,6,3,7,7} packed as nibbles
#define PA_PACK 0x36221400u
#define PB_PACK 0x77365514u

// ---------------- pre-kernel: yk stored as [ij][half][12] (12-padded halves,
// each half 16B-aligned: 2 b128 + 1 b64). ws[1536] = c0.
__global__ void yk_kernel(
    const float* __restrict__ mask,
    const float* __restrict__ wm1, const float* __restrict__ bm1,
    const float* __restrict__ wm2, const float* __restrict__ bm2,
    const float* __restrict__ wm3, const float* __restrict__ bm3,
    const float* __restrict__ wk1, const float* __restrict__ bk1,
    const float* __restrict__ wk2, const float* __restrict__ bk2,
    float* __restrict__ ws)
{
    int tid = threadIdx.x;
    int ij = tid >> 2, coff = (tid & 3) * 5;
    int i = ij >> 3, j = ij & 7;
    float m = mask[i * 8 + j];
    float a[4];
#pragma unroll
    for (int q = 0; q < 4; q++) a[q] = relu_(fmaf(m, wm1[q], bm1[q]));
    float b2[20];
#pragma unroll
    for (int c = 0; c < 20; c++) {
        float acc = bm2[c];
#pragma unroll
        for (int q = 0; q < 4; q++) acc = fmaf(a[q], wm2[q * 20 + c], acc);
        b2[c] = relu_(acc);
    }
#pragma unroll
    for (int cc = 0; cc < 5; cc++) {
        int c = coff + cc;
        float acc = bm3[c];
#pragma unroll
        for (int k = 0; k < 20; k++) acc = fmaf(b2[k], wm3[k * 20 + c], acc);
        float y = relu_(acc);
        float wkk = 0.f;
#pragma unroll
        for (int q = 0; q < 8; q++) wkk = fmaf(wk1[c * 8 + q], wk2[q], wkk);
        int half = (c >= 10), cc12 = c - 10 * half;
        ws[ij * 24 + half * 12 + cc12] = y * wkk;
    }
    if (tid == 0) {
        float c0 = bk2[0];
#pragma unroll
        for (int q = 0; q < 8; q++) c0 = fmaf(bk1[q], wk2[q], c0);
        ws[1536] = c0;
    }
}

// ---------------- main kernel: 4 batches/wave, lane=(g,jh,i) (R10 skeleton).
// All lanes compute pd row i and u row i (u stays in REGISTERS) and v row i;
// jh=1 lanes write v -> LDS. Stage 4: lane owns (i,jh), one j per iteration.
// All math on f32x2 with op_sel half-broadcast pk_fma (zero splat movs);
// weights always wave-uniform -> "s" operand from s_load. No launch_bounds.
__global__ void frap_kernel(
    const float* __restrict__ x,
    const float* __restrict__ wv1, const float* __restrict__ bv1,
    const float* __restrict__ wv2, const float* __restrict__ bv2,
    const float* __restrict__ wp1, const float* __restrict__ bp1,
    const float* __restrict__ wp2, const float* __restrict__ bp2,
    const float* __restrict__ we,  const float* __restrict__ be,
    const float* __restrict__ wc1, const float* __restrict__ bc1,
    const float* __restrict__ wc2, const float* __restrict__ bc2,
    const float* __restrict__ ykg,
    float* __restrict__ out, int Btot)
{
    // v rows only: (w,g) block at grp*164 dwords (164%32=4 -> group bank
    // offsets {0,4,...,28}x2: worst 2-way = free). Row j at +j*20 (8 distinct
    // bank spans). b128 reads 16B-aligned (656B block, 80B rows). 10.5 KB.
    __shared__ float s_v[16 * 164];

    const int tid  = threadIdx.x;
    const int w    = tid >> 6;
    const int lane = tid & 63;
    const int g    = lane >> 4;
    const int jh   = (lane >> 3) & 1;
    const int i    = lane & 7;
    const int grp  = w * 4 + g;
    const int gb   = grp * 164;
    const int b    = blockIdx.x * 16 + grp;
    const int bb   = (b < Btot) ? b : (Btot - 1);

    const int pa = (PA_PACK >> (4 * i)) & 15;
    const int pb = (PB_PACK >> (4 * i)) & 15;

    // ---- stage 1: cat rows pa,pb -> packed pairs ca2[4], cb2[4] ----
    f32x2 ca2[4], cb2[4];
    {
        const float xva = x[bb * 16 + pa];
        const float xpa = x[bb * 16 + 8 + pa];
        const float xvb = x[bb * 16 + pb];
        const float xpb = x[bb * 16 + 8 + pb];

        float t0 = relu_(fmaf(xva, wv1[0], bv1[0]));
        float t1 = relu_(fmaf(xva, wv1[1], bv1[1]));
#pragma unroll
        for (int q = 0; q < 4; q++) {
            float v = relu_(fmaf(t0, wv2[q], fmaf(t1, wv2[4 + q], bv2[q])));
            if (q & 1) ca2[q >> 1].y = v; else ca2[q >> 1].x = v;
        }
        float p0 = relu_(fmaf(xpa, wp1[0], bp1[0]));
        float p1 = relu_(fmaf(xpa, wp1[1], bp1[1]));
#pragma unroll
        for (int q = 0; q < 4; q++) {
            float v = relu_(fmaf(p0, wp2[q], fmaf(p1, wp2[4 + q], bp2[q])));
            if (q & 1) ca2[2 + (q >> 1)].y = v; else ca2[2 + (q >> 1)].x = v;
        }
        float s0 = relu_(fmaf(xvb, wv1[0], bv1[0]));
        float s1 = relu_(fmaf(xvb, wv1[1], bv1[1]));
#pragma unroll
        for (int q = 0; q < 4; q++) {
            float v = relu_(fmaf(s0, wv2[q], fmaf(s1, wv2[4 + q], bv2[q])));
            if (q & 1) cb2[q >> 1].y = v; else cb2[q >> 1].x = v;
        }
        float r0 = relu_(fmaf(xpb, wp1[0], bp1[0]));
        float r1 = relu_(fmaf(xpb, wp1[1], bp1[1]));
#pragma unroll
        for (int q = 0; q < 4; q++) {
            float v = relu_(fmaf(r0, wp2[q], fmaf(r1, wp2[4 + q], bp2[q])));
            if (q & 1) cb2[2 + (q >> 1)].y = v; else cb2[2 + (q >> 1)].x = v;
        }
    }

    // ---- stage 2: pd row i as 8 k-pairs, packed (f-order matches ref) ----
    f32x2 pd2[8];
    {
        f32x2 da2[8], db2[8];
#pragma unroll
        for (int kk = 0; kk < 8; kk++) {
            da2[kk] = *(const f32x2*)&be[2 * kk];   // SGPR pair init
            db2[kk] = da2[kk];
        }
#pragma unroll
        for (int qf = 0; qf < 4; qf++) {
#pragma unroll
            for (int kk = 0; kk < 8; kk++) {
                const f32x2 w0 = *(const f32x2*)&we[(2 * qf) * 16 + 2 * kk];
                const f32x2 w1 = *(const f32x2*)&we[(2 * qf + 1) * 16 + 2 * kk];
                pk_fma_blo(da2[kk], ca2[qf], w0);   // f = 2qf
                pk_fma_bhi(da2[kk], ca2[qf], w1);   // f = 2qf+1
                pk_fma_blo(db2[kk], cb2[qf], w0);
                pk_fma_bhi(db2[kk], cb2[qf], w1);
            }
        }
#pragma unroll
        for (int kk = 0; kk < 8; kk++) {
            da2[kk].x = relu_(da2[kk].x); da2[kk].y = relu_(da2[kk].y);
            db2[kk].x = relu_(db2[kk].x); db2[kk].y = relu_(db2[kk].y);
            pd2[kk] = da2[kk] + db2[kk];            // v_pk_add_f32
        }
    }

    // ---- stage 3: u row i -> u2[10] (regs); v row i -> LDS (jh=1 writes).
    //      c-half passes keep live ~46. Weight indices wave-uniform.
    f32x2 u2[10];
#pragma unroll
    for (int half = 0; half < 2; half++) {
        f32x2 aV[5];
#pragma unroll
        for (int c = 0; c < 5; c++) {
            u2[half * 5 + c] = *(const f32x2*)&bc1[half * 10 + 2 * c];
            aV[c].x = 0.f; aV[c].y = 0.f;
        }
#pragma unroll
        for (int kk = 0; kk < 8; kk++) {
#pragma unroll
            for (int c = 0; c < 5; c++) {
                pk_fma_blo(u2[half * 5 + c], pd2[kk],
                           *(const f32x2*)&wc1[(2 * kk) * 20 + half * 10 + 2 * c]);
                pk_fma_bhi(u2[half * 5 + c], pd2[kk],
                           *(const f32x2*)&wc1[(2 * kk + 1) * 20 + half * 10 + 2 * c]);
                pk_fma_blo(aV[c], pd2[kk],
                           *(const f32x2*)&wc1[(16 + 2 * kk) * 20 + half * 10 + 2 * c]);
                pk_fma_bhi(aV[c], pd2[kk],
                           *(const f32x2*)&wc1[(17 + 2 * kk) * 20 + half * 10 + 2 * c]);
            }
        }
        if (jh == 1) {
#pragma unroll
            for (int c = 0; c < 5; c++)
                *(f32x2*)&s_v[gb + i * 20 + half * 10 + 2 * c] = aV[c];
        }
    }
    wave_sync();   // per-wave LDS region; lockstep => visible wave-wide

    // NOTE: u2[p] holds columns {2p, 2p+1}, p = 0..9 (linear pair order).

    // ---- stage 4: lane owns (i, jh); four iterations, one j each ----
    const float c0 = ykg[1536];                     // uniform -> s_load

#pragma unroll 1
    for (int t = 0; t < 4; ++t) {
        const int j = jh * 4 + t;
        const float* vr = &s_v[gb + j * 20];

        f32x2 h[10];
#pragma unroll
        for (int p = 0; p < 5; p++) {
            f32x4 q = *(const f32x4*)&vr[4 * p];    // ds_read_b128 broadcast
            f32x2 lo; lo.x = q.x; lo.y = q.y;
            f32x2 hi; hi.x = q.z; hi.y = q.w;
            lo += u2[2 * p];                        // v_pk_add_f32
            hi += u2[2 * p + 1];
            lo.x = relu_(lo.x); lo.y = relu_(lo.y);
            hi.x = relu_(hi.x); hi.y = relu_(hi.y);
            h[2 * p] = lo; h[2 * p + 1] = hi;
        }

        f32x2 zz; zz.x = 0.f; zz.y = 0.f;
#pragma unroll
        for (int half = 0; half < 2; half++) {
            f32x2 s[5];
#pragma unroll
            for (int c = 0; c < 5; c++)
                s[c] = *(const f32x2*)&bc2[half * 10 + 2 * c];
#pragma unroll
            for (int kk = 0; kk < 10; kk++) {
#pragma unroll
                for (int c = 0; c < 5; c++) {
                    pk_fma_blo(s[c], h[kk],
                               *(const f32x2*)&wc2[(2 * kk) * 20 + half * 10 + 2 * c]);
                    pk_fma_bhi(s[c], h[kk],
                               *(const f32x2*)&wc2[(2 * kk + 1) * 20 + half * 10 + 2 * c]);
                }
            }
            // yk half: 2x b128 + 1x b64 (12-padded, aligned, L1-hot)
            const float* yh = ykg + (i * 8 + j) * 24 + half * 12;
            f32x4 y0 = *(const f32x4*)&yh[0];
            f32x4 y1 = *(const f32x4*)&yh[4];
            f32x2 y2 = *(const f32x2*)&yh[8];
#pragma unroll
            for (int c = 0; c < 5; c++) {
                s[c].x = relu_(s[c].x); s[c].y = relu_(s[c].y);
            }
            f32x2 p0; p0.x = y0.x; p0.y = y0.y;
            f32x2 p1; p1.x = y0.z; p1.y = y0.w;
            f32x2 p2; p2.x = y1.x; p2.y = y1.y;
            f32x2 p3; p3.x = y1.z; p3.y = y1.w;
            pk_fma_vv(zz, s[0], p0);
            pk_fma_vv(zz, s[1], p1);
            pk_fma_vv(zz, s[2], p2);
            pk_fma_vv(zz, s[3], p3);
            pk_fma_vv(zz, s[4], y2);
        }
        if (b < Btot)
            out[b * 64 + i * 8 + j] = c0 + zz.x + zz.y;
    }
}

extern "C" void kernel_launch(void* const* d_in, const int* in_sizes, int n_in,
                              void* d_out, int out_size, void* d_ws, size_t ws_size,
                              hipStream_t stream) {
    const float* x    = (const float*)d_in[0];
    const float* mask = (const float*)d_in[1];
    const float* wv1  = (const float*)d_in[2];
    const float* bv1  = (const float*)d_in[3];
    const float* wv2  = (const float*)d_in[4];
    const float* bv2  = (const float*)d_in[5];
    const float* wp1  = (const float*)d_in[6];
    const float* bp1  = (const float*)d_in[7];
    const float* wp2  = (const float*)d_in[8];
    const float* bp2  = (const float*)d_in[9];
    const float* we   = (const float*)d_in[10];
    const float* be   = (const float*)d_in[11];
    const float* wc1  = (const float*)d_in[12];
    const float* bc1  = (const float*)d_in[13];
    const float* wc2  = (const float*)d_in[14];
    const float* bc2  = (const float*)d_in[15];
    const float* wm1  = (const float*)d_in[16];
    const float* bm1  = (const float*)d_in[17];
    const float* wm2  = (const float*)d_in[18];
    const float* bm2  = (const float*)d_in[19];
    const float* wm3  = (const float*)d_in[20];
    const float* bm3  = (const float*)d_in[21];
    const float* wk1  = (const float*)d_in[22];
    const float* bk1  = (const float*)d_in[23];
    const float* wk2  = (const float*)d_in[24];
    const float* bk2  = (const float*)d_in[25];
    float* out = (float*)d_out;
    float* ws  = (float*)d_ws;

    int Btot = in_sizes[0] / 16;                 // 32768

    yk_kernel<<<1, 256, 0, stream>>>(mask, wm1, bm1, wm2, bm2, wm3, bm3,
                                     wk1, bk1, wk2, bk2, ws);

    int grid = (Btot + 15) / 16;                 // 2048 blocks, single shot
    frap_kernel<<<grid, 256, 0, stream>>>(
        x, wv1, bv1, wv2, bv2, wp1, bp1, wp2, bp2, we, be,
        wc1, bc1, wc2, bc2, ws, out, Btot);
}